// Round 6
// baseline (279.388 us; speedup 1.0000x reference)
//
#include <hip/hip_runtime.h>
#include <cstddef>

// Problem shape (fixed): N=50000, K=16, C_IN=128, C2=256, C_OUT=128.
#define C_IN  128
#define C2    256
#define C_OUT 128
#define KNBR  16
#define PTS   32     // points per gather_out block

typedef unsigned short u16;
typedef __attribute__((ext_vector_type(8))) short bf16x8;   // 8 bf16 (4 VGPRs)
typedef __attribute__((ext_vector_type(8))) unsigned short u16x8; // 16B payload
typedef __attribute__((ext_vector_type(4))) float f32x4;

__device__ __forceinline__ float bf2f(u16 h) {
    return __uint_as_float(((unsigned int)h) << 16);
}
__device__ __forceinline__ u16 f2bf(float x) {
    unsigned int u = __float_as_uint(x);
    return (u16)((u + 0x7fffu + ((u >> 16) & 1u)) >> 16);
}

// Transpose + convert weights to bf16, n-major [N][K]; fold BN params.
__global__ void prep_k(const float* __restrict__ W1, const float* __restrict__ Ws,
                       const float* __restrict__ Wm, const float* __restrict__ b1,
                       const float* __restrict__ gamma, const float* __restrict__ beta,
                       const float* __restrict__ mean, const float* __restrict__ var,
                       u16* __restrict__ W1t, u16* __restrict__ Wst,
                       u16* __restrict__ Wmt, float4* __restrict__ bnp)
{
    const int n = blockIdx.x, t = threadIdx.x;
    if (blockIdx.y == 0) {
        if (t < 128) W1t[n * 128 + t] = f2bf(W1[t * 256 + n]);
    } else if (blockIdx.y == 1) {
        Wst[n * 256 + t] = f2bf(Ws[t * 256 + n]);
    } else if (blockIdx.y == 2) {
        if (n < 128) Wmt[n * 256 + t] = f2bf(Wm[t * 128 + n]);
    } else if (n == 0) {
        // x = (relu(z+b1)-mu)*iv + be = relu(z+c1)*c2 + c3
        float iv = gamma[t] * rsqrtf(var[t] + 1e-5f);
        bnp[t] = make_float4(b1[t], iv, beta[t] - mean[t] * iv, 0.f);
    }
}

// ---------------------------------------------------------------------------
// LESSONS ENCODED:
//  R7:  accumulator arrays indexed by non-unrolled loop vars spill to scratch.
//  R9:  scattered sub-dword global stores -> write-allocate RMW (16x bytes).
//  R10: 1-block/CU weight-stationary waves have zero latency hiding.
//  R11: packed row CHANNEL-INTERLEAVED [ey0,x0,ey1,x1,...]: one dwordx4/lane
//       per neighbor row; e,x same lane for the FMA.
//  R12: gather moves 800 MB LOGICAL bytes in ~121 us (~6.6 TB/s CU<->cache) —
//       copy-ceiling class. FETCH ~370 MB structural. Leave it alone.
//  R14: launch_bounds cap below per-PHASE live state => silent scratch spill.
//       Audit live VGPRs per phase before capping.
//  R15: GEMM2's ey(row,col) lane == GEMM1's x(row,col) lane -> keep x in
//       VGPRs, store (ey|x<<16) dword lane-locally. No ey LDS staging.
//  R16 (this round): mlp_k ~115 us by subtraction vs ~20 us cycle model, but
//       ZERO direct counters (never in top-5). (a) split gather into 521+1042
//       block dispatches (~40/~80 us each) so mlp>=80 MUST surface in top-5;
//       (b) occupancy experiment: drop As tile, A-frags direct to regs ->
//       LDS 69.6->52.2 KB -> 3 blocks/CU (12 waves), cap (256,3)=170 VGPR,
//       audited peak ~130.
// packed row (512 u16): 256 pairs of (ey[c], x[c]), both bf16.
// ---------------------------------------------------------------------------

// Fused MLP, 64-row blocks (52.2 KB LDS -> 3 blocks/CU), 4 waves (2M x 2N):
//   GEMM1: x = BN(relu(F @ W1 + b1)) -> xs (LDS, for GEMM2-A) + xr (VGPR)
//   GEMM2: ey = exp(x @ Ws) -> lane-local interleaved (ey|x) dword stores
__global__ __launch_bounds__(256, 3)
void mlp_k(const float* __restrict__ F, const u16* __restrict__ W1t,
           const u16* __restrict__ Wst, const float4* __restrict__ bnp,
           u16* __restrict__ packed, int N)
{
    __shared__ u16 Bs[128][72];    // weight k-slice staging   (18.4 KB)
    __shared__ u16 xs[64][264];    // x tile, full K=256       (33.8 KB)

    const int tid = threadIdx.x;
    const int w = tid >> 6, l = tid & 63, q = l >> 4, r = l & 15;
    const int wm = w & 1, wn = w >> 1;
    const int m0 = blockIdx.x * 64;

    // ---- A-fragments direct from F into regs (no As tile): af1[i][kt] ----
    // lane (q,r), row m0+wm*32+i*16+r, k-slice kt*32+q*8..+8 (two float4).
    bf16x8 af1[2][4];
    #pragma unroll
    for (int i = 0; i < 2; i++) {
        const int gr = m0 + wm * 32 + i * 16 + r;
        #pragma unroll
        for (int t = 0; t < 4; t++) {
            float4 v0 = make_float4(0.f, 0.f, 0.f, 0.f), v1 = v0;
            if (gr < N) {
                const float* s = F + (size_t)gr * C_IN + t * 32 + q * 8;
                v0 = *(const float4*)s;
                v1 = *(const float4*)(s + 4);
            }
            bf16x8 a;
            a[0] = (short)f2bf(v0.x); a[1] = (short)f2bf(v0.y);
            a[2] = (short)f2bf(v0.z); a[3] = (short)f2bf(v0.w);
            a[4] = (short)f2bf(v1.x); a[5] = (short)f2bf(v1.y);
            a[6] = (short)f2bf(v1.z); a[7] = (short)f2bf(v1.w);
            af1[i][t] = a;
        }
    }

    // x kept in registers, bf16-packed: [nh][i][j] ushort4
    ushort4 xr[2][2][4];

    // ---- GEMM1: x = F @ W1, two 128-col halves (A from regs) ----
    #pragma unroll
    for (int nh = 0; nh < 2; nh++) {
        f32x4 acc[2][4] = {};
        #pragma unroll 1
        for (int k0 = 0; k0 < C_IN; k0 += 64) {
            __syncthreads();   // prior Bs readers done
            #pragma unroll
            for (int i = 0; i < 4; i++) {
                int idx = tid + i * 256;
                int row = idx >> 3, g = (idx & 7) * 8;
                *(uint4*)&Bs[row][g] = *(const uint4*)(
                    W1t + (size_t)(nh * 128 + row) * C_IN + k0 + g);
            }
            __syncthreads();
            #pragma unroll
            for (int h = 0; h < 2; h++) {
                const int kt = (k0 >> 5) + h;
                bf16x8 bfr[4];
                #pragma unroll
                for (int j = 0; j < 4; j++)
                    bfr[j] = *(const bf16x8*)&Bs[wn * 64 + j * 16 + r][h * 32 + q * 8];
                #pragma unroll
                for (int i = 0; i < 2; i++)
                    #pragma unroll
                    for (int j = 0; j < 4; j++)
                        acc[i][j] = __builtin_amdgcn_mfma_f32_16x16x32_bf16(
                            af1[i][kt], bfr[j], acc[i][j], 0, 0, 0);
            }
        }
        // epilogue 1: x = relu(z+c1)*c2+c3 -> xs (LDS) AND xr (VGPR, bf16)
        #pragma unroll
        for (int j = 0; j < 4; j++) {
            const int ch = nh * 128 + wn * 64 + j * 16 + r;
            const float4 bp = bnp[ch];
            #pragma unroll
            for (int i = 0; i < 2; i++) {
                const int mb = wm * 32 + i * 16 + q * 4;
                ushort4 hx;
                #pragma unroll
                for (int p = 0; p < 4; p++) {
                    float x = fmaxf(acc[i][j][p] + bp.x, 0.f) * bp.y + bp.z;
                    u16 h = f2bf(x);
                    xs[mb + p][ch] = h;
                    if (p == 0) hx.x = h; else if (p == 1) hx.y = h;
                    else if (p == 2) hx.z = h; else hx.w = h;
                }
                xr[nh][i][j] = hx;
            }
        }
    }

    // ---- GEMM2: ey = exp(x @ Ws); A from xs; direct lane-local epilogue ----
    #pragma unroll
    for (int nh = 0; nh < 2; nh++) {
        f32x4 acc[2][4] = {};
        #pragma unroll 1
        for (int k0 = 0; k0 < C2; k0 += 64) {
            __syncthreads();   // prior Bs readers done; 1st iter: xs complete
            #pragma unroll
            for (int i = 0; i < 4; i++) {
                int idx = tid + i * 256;
                int row = idx >> 3, g = (idx & 7) * 8;
                *(uint4*)&Bs[row][g] = *(const uint4*)(
                    Wst + (size_t)(nh * 128 + row) * C2 + k0 + g);
            }
            __syncthreads();
            #pragma unroll
            for (int h = 0; h < 2; h++) {
                bf16x8 af[2], bfr[4];
                #pragma unroll
                for (int i = 0; i < 2; i++)
                    af[i] = *(const bf16x8*)&xs[wm * 32 + i * 16 + r][k0 + h * 32 + q * 8];
                #pragma unroll
                for (int j = 0; j < 4; j++)
                    bfr[j] = *(const bf16x8*)&Bs[wn * 64 + j * 16 + r][h * 32 + q * 8];
                #pragma unroll
                for (int i = 0; i < 2; i++)
                    #pragma unroll
                    for (int j = 0; j < 4; j++)
                        acc[i][j] = __builtin_amdgcn_mfma_f32_16x16x32_bf16(
                            af[i], bfr[j], acc[i][j], 0, 0, 0);
            }
        }
        // epilogue 2: ey=exp(acc); pair with register-held x (layout identity)
        #pragma unroll
        for (int j = 0; j < 4; j++) {
            const int ch = nh * 128 + wn * 64 + j * 16 + r;
            #pragma unroll
            for (int i = 0; i < 2; i++) {
                const int mb = wm * 32 + i * 16 + q * 4;
                const ushort4 hx = xr[nh][i][j];
                #pragma unroll
                for (int p = 0; p < 4; p++) {
                    const int gm = m0 + mb + p;
                    if (gm < N) {
                        unsigned xv = (p == 0) ? hx.x : (p == 1) ? hx.y
                                    : (p == 2) ? hx.z : hx.w;
                        unsigned ey = f2bf(__expf(acc[i][j][p]));
                        *(unsigned*)(packed + (size_t)gm * 512 + ch * 2) =
                            ey | (xv << 16);
                    }
                }
            }
        }
    }
}

// Fused gather + attentive pool + output GEMM. 32 points/block, 4 waves.
// Phase 1: each wave pools 8 points; 16 rows gathered in TWO passes of 8
//          (32-VGPR payload, fits under the (256,5) cap -> no scratch).
// Phase 2: out[32 x 128] = feat @ Wmt + bm, B direct from L2-resident Wmt;
//          fp32 epilogue staging ALIASES the feat buffer.
// b0: block-index offset (grid split into two dispatches for profiling).
__global__ __launch_bounds__(256, 5)
void gather_out_k(const u16* __restrict__ packed, const int* __restrict__ nidx,
                  const u16* __restrict__ Bt, const float* __restrict__ bias,
                  float* __restrict__ Cf, int b0, int N)
{
    __shared__ int rows[PTS * KNBR];                 // 2 KB
    __shared__ __align__(16) u16 fsm[PTS * 264];     // feat bf16 / STF fp32 alias

    const int tid = threadIdx.x;
    const int w = tid >> 6, l = tid & 63, q = l >> 4, r = l & 15;
    const int m0 = (b0 + blockIdx.x) * PTS;

    // stage neighbor indices: PTS*16 = 512 ints, 2/thread
    #pragma unroll
    for (int i = 0; i < 2; i++) {
        int idx = tid + i * 256;
        int n = m0 + (idx >> 4);
        rows[idx] = (n < N) ? nidx[n * KNBR + (idx & 15)] : 0;
    }
    __syncthreads();

    // ---- phase 1: gather + pool, wave w -> points w*8 .. w*8+7 ----
    #pragma unroll 1
    for (int ip = 0; ip < 8; ip++) {
        const int pl = w * 8 + ip;
        float num[4] = {0.f, 0.f, 0.f, 0.f};
        float den[4] = {0.f, 0.f, 0.f, 0.f};
        #pragma unroll 1
        for (int hf = 0; hf < 2; hf++) {
            u16x8 v[8];
            #pragma unroll
            for (int k = 0; k < 8; k++)
                v[k] = *(const u16x8*)(packed +
                    (size_t)rows[pl * KNBR + hf * 8 + k] * 512 + l * 8);
            #pragma unroll
            for (int k = 0; k < 8; k++) {
                #pragma unroll
                for (int c = 0; c < 4; c++) {
                    float e = bf2f((u16)v[k][2 * c]);
                    float x = bf2f((u16)v[k][2 * c + 1]);
                    den[c] += e;
                    num[c] = fmaf(e, x, num[c]);
                }
            }
        }
        ushort4 o;
        o.x = f2bf(num[0] / den[0]); o.y = f2bf(num[1] / den[1]);
        o.z = f2bf(num[2] / den[2]); o.w = f2bf(num[3] / den[3]);
        *(ushort4*)&fsm[pl * 264 + l * 4] = o;   // rows >= N: garbage, never stored
    }
    __syncthreads();   // feat tile complete

    // ---- phase 2: out GEMM, wave grid 2M x 2N; B direct from L2 ----
    const int wm = w & 1, wn = w >> 1;
    f32x4 acc[4] = {};

    #pragma unroll
    for (int k0 = 0; k0 < C2; k0 += 64) {
        #pragma unroll
        for (int h = 0; h < 2; h++) {
            bf16x8 af, bfr[4];
            af = *(const bf16x8*)&fsm[(wm * 16 + r) * 264 + k0 + h * 32 + q * 8];
            #pragma unroll
            for (int j = 0; j < 4; j++)
                bfr[j] = *(const bf16x8*)(Bt +
                    (size_t)(wn * 64 + j * 16 + r) * C2 + k0 + h * 32 + q * 8);
            #pragma unroll
            for (int j = 0; j < 4; j++)
                acc[j] = __builtin_amdgcn_mfma_f32_16x16x32_bf16(
                    af, bfr[j], acc[j], 0, 0, 0);
        }
    }
    __syncthreads();   // all feat reads done -> safe to alias STF onto fsm

    // epilogue: stage fp32 tile in aliased LDS, then full-line float4 flush
    float* STF = (float*)fsm;              // [32][132]
    #pragma unroll
    for (int j = 0; j < 4; j++) {
        const int ch = wn * 64 + j * 16 + r;
        const float bo = bias[ch];
        const int mb = wm * 16 + q * 4;
        #pragma unroll
        for (int p = 0; p < 4; p++)
            STF[(mb + p) * 132 + ch] = acc[j][p] + bo;
    }
    __syncthreads();
    #pragma unroll
    for (int i = 0; i < 4; i++) {          // 32x128 fp32 = 1024 float4
        int idx = tid + i * 256;
        int row = idx >> 5, c4 = (idx & 31) * 4;
        if (m0 + row < N)
            *(float4*)(Cf + (size_t)(m0 + row) * C_OUT + c4) =
                *(const float4*)&STF[row * 132 + c4];
    }
}

extern "C" void kernel_launch(void* const* d_in, const int* in_sizes, int n_in,
                              void* d_out, int out_size, void* d_ws, size_t ws_size,
                              hipStream_t stream)
{
    const float* features = (const float*)d_in[0];
    const int*   nidx     = (const int*)d_in[1];
    const float* W1       = (const float*)d_in[2];
    const float* b1       = (const float*)d_in[3];
    const float* gamma    = (const float*)d_in[4];
    const float* beta     = (const float*)d_in[5];
    const float* mean     = (const float*)d_in[6];
    const float* var      = (const float*)d_in[7];
    const float* Ws       = (const float*)d_in[8];
    const float* Wm       = (const float*)d_in[9];
    const float* bm       = (const float*)d_in[10];
    float* out = (float*)d_out;

    const int N = in_sizes[0] / C_IN;   // 50000

    u16* packed = (u16*)d_ws;                      // N x 512 interleaved pairs
    u16* W1t    = packed + (size_t)N * 512;        // 256 x 128
    u16* Wst    = W1t + 256 * 128;                 // 256 x 256
    u16* Wmt    = Wst + 256 * 256;                 // 128 x 256
    float4* bnp = (float4*)(Wmt + 128 * 256);      // 256 folded BN params

    prep_k<<<dim3(256, 4), 256, 0, stream>>>(W1, Ws, Wm, b1, gamma, beta,
                                             mean, var, W1t, Wst, Wmt, bnp);

    const int MT = (N + 63) / 64;        // 782
    const int GT = (N + PTS - 1) / PTS;  // 1563
    const int G1 = 521;                  // split: both halves < 1280 resident

    mlp_k<<<MT, 256, 0, stream>>>(features, W1t, Wst, bnp, packed, N);
    gather_out_k<<<G1, 256, 0, stream>>>(packed, nidx, Wmt, bm, out, 0, N);
    gather_out_k<<<GT - G1, 256, 0, stream>>>(packed, nidx, Wmt, bm, out, G1, N);
}